// Round 3
// baseline (428.097 us; speedup 1.0000x reference)
//
#include <hip/hip_runtime.h>
#include <math.h>

// ---------------------------------------------------------------------------
// B=4, S=8192, D=1024, H=4, hd=256.
// Static lattice: positions {12,36,104,304,888,2592,7568}; 16 entries
// (level-major: L1 E0..E6, L2 E7..E12, L3 E13..E15).
//
// ONE persistent kernel:
//   blocks [0,256)  : 9-stage chain, ordered by device-scope atomic barriers
//                     (then they join the copy pool)
//   blocks [256,1024): stream-copy x->out (skipping the 28 updated rows) via
//                     wave-level atomic work stealing, nontemporal loads/stores.
// Co-residency: __launch_bounds__(256,4) -> <=128 VGPR -> 4 blocks/CU ->
// 1024 blocks all resident; copy blocks never wait on chain, so no deadlock.
// ---------------------------------------------------------------------------

#define SEQ 8192
#define DM  1024
#define NB        1024
#define CHAIN     256
#define NCHUNK    8192u          // 8,388,608 float4 / 1024 per chunk

typedef float fx4 __attribute__((ext_vector_type(4)));

__device__ __constant__ int c_nodes[16][3] = {
  {0,2,4},{2,4,12},{4,12,36},{12,36,104},{36,104,304},{104,304,888},{304,888,2592},
  {0,0,0},{0,2,0},{0,2,4},{2,4,12},{4,12,36},{12,36,104},
  {0,0,0},{0,2,0},{0,2,4}};
__device__ __constant__ float c_wt[16][3] = {
  {1,1,1},{1,1,1},{1,1,1},{1,1,1},{1,1,1},{1,1,1},{1,1,1},
  {1,0,0},{1,1,0},{1,1,1},{1,2,3},{1,2,3},{1,2,3},
  {1,0,0},{1,1,0},{1,1,1}};
__device__ __constant__ float c_winv[16] = {
  1.f/3.f,1.f/3.f,1.f/3.f,1.f/3.f,1.f/3.f,1.f/3.f,1.f/3.f,
  1.f,0.5f,1.f/3.f,1.f/6.f,1.f/6.f,1.f/6.f,
  1.f,0.5f,1.f/3.f};
__device__ __constant__ int c_pos[7]  = {12,36,104,304,888,2592,7568};
__device__ __constant__ int c_ne[7]   = {1,2,2,2,3,3,3};
__device__ __constant__ int c_posE[7][3] = {
  {0,0,0},{1,7,0},{2,8,0},{3,9,0},{4,10,13},{5,11,14},{6,12,15}};

// 8-row chunk tables for the lattice GEMMs (rows of F/Hh, entry-major):
// L1 rows [0,28), L2 [28,52), L3 [52,64)
__device__ __constant__ int c_lr0[9]  = {0,8,16,24,28,36,44,52,60};
__device__ __constant__ int c_lnr[9]  = {8,8,8,4,8,8,8,8,4};
__device__ __constant__ int c_llv[9]  = {0,0,0,0,1,1,1,2,2};
// qkv chunks: 0..3 = Q rows of QIN(28)
__device__ __constant__ int c_qr0[4]  = {0,8,16,24};
__device__ __constant__ int c_qnr[4]  = {8,8,8,4};
// 28-row chunks (out-proj / fusion)
__device__ __constant__ int c_or0[4]  = {0,8,16,24};
__device__ __constant__ int c_onr[4]  = {8,8,8,4};

// ---------------------------------------------------------------------------
// device-scope barrier among the CHAIN blocks only
// ---------------------------------------------------------------------------
__device__ __forceinline__ void gbar(unsigned* __restrict__ bar, int phase)
{
  __syncthreads();
  if (threadIdx.x == 0) {
    __threadfence();
    atomicAdd(&bar[phase], 1u);
    while (atomicAdd(&bar[phase], 0u) < (unsigned)CHAIN)
      __builtin_amdgcn_s_sleep(16);
    __threadfence();
  }
  __syncthreads();
}

// ---------------------------------------------------------------------------
// GEMM task: Y[r0..r0+nr)[jt*16..+16) = X(nr rows, stride K) * W^T + bias.
// 4 waves/block, wave handles 4 consecutive j; lanes over k (float4).
// ---------------------------------------------------------------------------
__device__ __forceinline__ void gemm8(const float* __restrict__ X,
                                      const float* __restrict__ W,
                                      const float* __restrict__ Bv,
                                      float* __restrict__ Y,
                                      int r0, int nr, int jt, int K, int ldy)
{
  const int lane = threadIdx.x & 63;
  const int wv   = threadIdx.x >> 6;
  const int jbase = jt * 16 + wv * 4;

  float a0[8], a1[8], a2[8], a3[8];
#pragma unroll
  for (int r = 0; r < 8; ++r) { a0[r]=0.f; a1[r]=0.f; a2[r]=0.f; a3[r]=0.f; }

  const int T = K >> 8;
  for (int t = 0; t < T; ++t) {
    const int k = t * 256 + lane * 4;
    const float4 w0 = *(const float4*)(W + (size_t)(jbase+0)*K + k);
    const float4 w1 = *(const float4*)(W + (size_t)(jbase+1)*K + k);
    const float4 w2 = *(const float4*)(W + (size_t)(jbase+2)*K + k);
    const float4 w3 = *(const float4*)(W + (size_t)(jbase+3)*K + k);
#pragma unroll
    for (int r = 0; r < 8; ++r) {
      const int rr = (r < nr) ? r : (nr - 1);
      const float4 xv = *(const float4*)(X + (size_t)(r0+rr)*K + k);
      a0[r] += w0.x*xv.x + w0.y*xv.y + w0.z*xv.z + w0.w*xv.w;
      a1[r] += w1.x*xv.x + w1.y*xv.y + w1.z*xv.z + w1.w*xv.w;
      a2[r] += w2.x*xv.x + w2.y*xv.y + w2.z*xv.z + w2.w*xv.w;
      a3[r] += w3.x*xv.x + w3.y*xv.y + w3.z*xv.z + w3.w*xv.w;
    }
  }
#pragma unroll
  for (int r = 0; r < 8; ++r) {
    float v0 = a0[r], v1 = a1[r], v2 = a2[r], v3 = a3[r];
#pragma unroll
    for (int off = 32; off >= 1; off >>= 1) {
      v0 += __shfl_xor(v0, off); v1 += __shfl_xor(v1, off);
      v2 += __shfl_xor(v2, off); v3 += __shfl_xor(v3, off);
    }
    a0[r] = v0; a1[r] = v1; a2[r] = v2; a3[r] = v3;
  }
  if (lane == 0) {
    const float b0 = Bv[jbase+0], b1 = Bv[jbase+1];
    const float b2 = Bv[jbase+2], b3 = Bv[jbase+3];
#pragma unroll
    for (int r = 0; r < 8; ++r) {
      if (r < nr) {
        float* yr = Y + (size_t)(r0+r)*ldy + jbase;
        yr[0] = a0[r]+b0; yr[1] = a1[r]+b1; yr[2] = a2[r]+b2; yr[3] = a3[r]+b3;
      }
    }
  }
}

// block mean/rstd over one 1024-row (256 threads x 4 elems)
__device__ __forceinline__ void block_mv(float s, float q, float* mean, float* rstd)
{
  __shared__ float s1[4], s2[4];
  const int lane = threadIdx.x & 63, wv = threadIdx.x >> 6;
#pragma unroll
  for (int off = 32; off >= 1; off >>= 1) {
    s += __shfl_xor(s, off); q += __shfl_xor(q, off);
  }
  if (lane == 0) { s1[wv] = s; s2[wv] = q; }
  __syncthreads();
  const float ts = s1[0]+s1[1]+s1[2]+s1[3];
  const float tq = s2[0]+s2[1]+s2[2]+s2[3];
  const float m = ts * (1.f/1024.f);
  *mean = m;
  *rstd = rsqrtf(tq * (1.f/1024.f) - m*m + 1e-5f);
}

// ---------------------------------------------------------------------------
// The mega kernel
// ---------------------------------------------------------------------------
__global__ __launch_bounds__(256, 4)
void k_mega(const float* __restrict__ x,
            const float* __restrict__ lt_w1, const float* __restrict__ lt_b1,
            const float* __restrict__ lt_ln_g, const float* __restrict__ lt_ln_b,
            const float* __restrict__ lt_w2, const float* __restrict__ lt_b2,
            const float* __restrict__ attn_in_w, const float* __restrict__ attn_in_b,
            const float* __restrict__ attn_out_w, const float* __restrict__ attn_out_b,
            const float* __restrict__ fus_w, const float* __restrict__ fus_b,
            const float* __restrict__ fus_ln_g, const float* __restrict__ fus_ln_b,
            float* __restrict__ out, float* __restrict__ ws)
{
  unsigned* bar = (unsigned*)ws;          // bar[0..7]
  unsigned* ctr = (unsigned*)ws + 8;      // copy work counter
  float* F   = ws + 256;                  // 64 x 1024
  float* Hh  = F   + 65536;               // 64 x 1024
  float* KV  = Hh  + 65536;               // 64 x 1024
  float* QIN = KV  + 65536;               // 32 x 1024 (28 valid)
  float* QH  = QIN + 32768;               // 32 x 1024
  float* KH  = QH  + 32768;               // 64 x 1024
  float* VH  = KH  + 65536;               // 64 x 1024
  float* OA  = VH  + 65536;               // 32 x 1024
  float* CB  = OA  + 32768;               // 32 x 2048  ([o | q])
  float* UP  = CB  + 65536;               // 32 x 1024

  const int cb = blockIdx.x;

  if (cb < CHAIN) {
    // ---- S0: lattice feature means + gather q rows --------------------
    for (int task = cb; task < 92; task += CHAIN) {
      const int d = threadIdx.x * 4;
      if (task < 64) {
        const int e = task >> 2, b = task & 3;
        float4 s = make_float4(0.f,0.f,0.f,0.f);
#pragma unroll
        for (int n = 0; n < 3; ++n) {
          const float w = c_wt[e][n];
          const float4 v = *(const float4*)(x + ((size_t)b*SEQ + c_nodes[e][n])*DM + d);
          s.x += w*v.x; s.y += w*v.y; s.z += w*v.z; s.w += w*v.w;
        }
        const float inv = c_winv[e];
        s.x*=inv; s.y*=inv; s.z*=inv; s.w*=inv;
        *(float4*)(F + (size_t)(e*4+b)*DM + d) = s;
      } else {
        const int i = task - 64;            // 0..27
        const int p = i >> 2, b = i & 3;
        const float4 v = *(const float4*)(x + ((size_t)b*SEQ + c_pos[p])*DM + d);
        *(float4*)(QIN + (size_t)i*DM + d) = v;
        *(float4*)(CB + (size_t)i*2048 + 1024 + d) = v;
      }
    }
    gbar(bar, 0);

    // ---- S1: H = F @ lt_w1^T + b1 (per level) -------------------------
    for (int task = cb; task < 576; task += CHAIN) {
      const int ch = task >> 6, jt = task & 63;
      const int lvl = c_llv[ch];
      gemm8(F, lt_w1 + (size_t)lvl*DM*DM, lt_b1 + lvl*DM, Hh,
            c_lr0[ch], c_lnr[ch], jt, DM, DM);
    }
    gbar(bar, 1);

    // ---- S2: LN + exact GELU in place on Hh ---------------------------
    for (int row = cb; row < 64; row += CHAIN) {
      const int e = row >> 2;
      const int lvl = (e < 7) ? 0 : ((e < 13) ? 1 : 2);
      const int j = threadIdx.x * 4;
      float* hr = Hh + (size_t)row*DM + j;
      float4 v = *(float4*)hr;
      float mean, rstd;
      block_mv(v.x+v.y+v.z+v.w, v.x*v.x+v.y*v.y+v.z*v.z+v.w*v.w, &mean, &rstd);
      const float* gg = lt_ln_g + lvl*DM + j;
      const float* bb = lt_ln_b + lvl*DM + j;
      const float t0 = (v.x-mean)*rstd*gg[0] + bb[0];
      const float t1 = (v.y-mean)*rstd*gg[1] + bb[1];
      const float t2 = (v.z-mean)*rstd*gg[2] + bb[2];
      const float t3 = (v.w-mean)*rstd*gg[3] + bb[3];
      const float kc = 0.70710678118654752f;
      v.x = 0.5f*t0*(1.f+erff(t0*kc));
      v.y = 0.5f*t1*(1.f+erff(t1*kc));
      v.z = 0.5f*t2*(1.f+erff(t2*kc));
      v.w = 0.5f*t3*(1.f+erff(t3*kc));
      *(float4*)hr = v;
    }
    gbar(bar, 2);

    // ---- S3: KV = H @ lt_w2^T + b2 ------------------------------------
    for (int task = cb; task < 576; task += CHAIN) {
      const int ch = task >> 6, jt = task & 63;
      const int lvl = c_llv[ch];
      gemm8(Hh, lt_w2 + (size_t)lvl*DM*DM, lt_b2 + lvl*DM, KV,
            c_lr0[ch], c_lnr[ch], jt, DM, DM);
    }
    gbar(bar, 3);

    // ---- S4: Q/K/V projections ----------------------------------------
    for (int task = cb; task < 1280; task += CHAIN) {
      const int ch = task >> 6, jt = task & 63;
      if (ch < 4)
        gemm8(QIN, attn_in_w, attn_in_b, QH, c_qr0[ch], c_qnr[ch], jt, DM, DM);
      else if (ch < 12)
        gemm8(KV, attn_in_w + (size_t)DM*DM, attn_in_b + DM, KH,
              (ch-4)*8, 8, jt, DM, DM);
      else
        gemm8(KV, attn_in_w + (size_t)2*DM*DM, attn_in_b + 2*DM, VH,
              (ch-12)*8, 8, jt, DM, DM);
    }
    gbar(bar, 4);

    // ---- S5: attention (block = (p,b), wave = head) -------------------
    for (int task = cb; task < 28; task += CHAIN) {
      const int p = task >> 2, b = task & 3;
      const int h = threadIdx.x >> 6, lane = threadIdx.x & 63;
      const int ne = c_ne[p];
      const int qoff = (p*4+b)*DM + h*256 + lane;
      const float q0 = QH[qoff], q1 = QH[qoff+64], q2 = QH[qoff+128], q3 = QH[qoff+192];
      float sc0 = -1e30f, sc1 = -1e30f, sc2 = -1e30f;
      int k0 = 0, k1 = 0, k2 = 0;
      {
        k0 = (c_posE[p][0]*4 + b)*DM + h*256 + lane;
        float pr = q0*KH[k0] + q1*KH[k0+64] + q2*KH[k0+128] + q3*KH[k0+192];
#pragma unroll
        for (int off = 32; off >= 1; off >>= 1) pr += __shfl_xor(pr, off);
        sc0 = pr * 0.0625f;
      }
      if (ne > 1) {
        k1 = (c_posE[p][1]*4 + b)*DM + h*256 + lane;
        float pr = q0*KH[k1] + q1*KH[k1+64] + q2*KH[k1+128] + q3*KH[k1+192];
#pragma unroll
        for (int off = 32; off >= 1; off >>= 1) pr += __shfl_xor(pr, off);
        sc1 = pr * 0.0625f;
      }
      if (ne > 2) {
        k2 = (c_posE[p][2]*4 + b)*DM + h*256 + lane;
        float pr = q0*KH[k2] + q1*KH[k2+64] + q2*KH[k2+128] + q3*KH[k2+192];
#pragma unroll
        for (int off = 32; off >= 1; off >>= 1) pr += __shfl_xor(pr, off);
        sc2 = pr * 0.0625f;
      }
      const float m = fmaxf(sc0, fmaxf(sc1, sc2));
      const float e0 = expf(sc0 - m);
      const float e1 = (ne > 1) ? expf(sc1 - m) : 0.f;
      const float e2 = (ne > 2) ? expf(sc2 - m) : 0.f;
      const float inv = 1.f / (e0+e1+e2);
      const float A0 = e0*inv, A1 = e1*inv, A2 = e2*inv;
#pragma unroll
      for (int i = 0; i < 4; ++i) {
        float o = A0 * VH[k0 + i*64];
        if (ne > 1) o += A1 * VH[k1 + i*64];
        if (ne > 2) o += A2 * VH[k2 + i*64];
        OA[qoff + i*64] = o;
      }
    }
    gbar(bar, 5);

    // ---- S6: out-projection into CB[:, 0:1024) ------------------------
    for (int task = cb; task < 256; task += CHAIN) {
      const int ch = task >> 6, jt = task & 63;
      gemm8(OA, attn_out_w, attn_out_b, CB, c_or0[ch], c_onr[ch], jt, DM, 2048);
    }
    gbar(bar, 6);

    // ---- S7: fusion GEMM (K = 2048) -----------------------------------
    for (int task = cb; task < 256; task += CHAIN) {
      const int ch = task >> 6, jt = task & 63;
      gemm8(CB, fus_w, fus_b, UP, c_or0[ch], c_onr[ch], jt, 2048, DM);
    }
    gbar(bar, 7);

    // ---- S8: final LN + scatter 28 rows into out ----------------------
    for (int row = cb; row < 28; row += CHAIN) {
      const int p = row >> 2, b = row & 3;
      const int j = threadIdx.x * 4;
      const float4 v = *(const float4*)(UP + (size_t)row*DM + j);
      float mean, rstd;
      block_mv(v.x+v.y+v.z+v.w, v.x*v.x+v.y*v.y+v.z*v.z+v.w*v.w, &mean, &rstd);
      const float* gg = fus_ln_g + j;
      const float* bb = fus_ln_b + j;
      float4 o;
      o.x = (v.x-mean)*rstd*gg[0] + bb[0];
      o.y = (v.y-mean)*rstd*gg[1] + bb[1];
      o.z = (v.z-mean)*rstd*gg[2] + bb[2];
      o.w = (v.w-mean)*rstd*gg[3] + bb[3];
      *(float4*)(out + ((size_t)b*SEQ + c_pos[p])*DM + j) = o;
    }
    // no barrier — fall through to help with the copy
  }

  // ---- copy pool: x -> out, skipping the 28 updated rows --------------
  {
    const int lane = threadIdx.x & 63;
    const fx4* __restrict__ src4 = (const fx4*)x;
    fx4* __restrict__ dst4 = (fx4*)out;
    for (;;) {
      unsigned c = 0;
      if (lane == 0) c = atomicAdd(ctr, 1u);
      c = (unsigned)__shfl((int)c, 0);
      if (c >= NCHUNK) break;
      const size_t base = (size_t)c * 1024;   // 1024 float4 = 4 rows
      const int row0 = (int)c * 4;
#pragma unroll
      for (int g = 0; g < 4; ++g) {
        const int s = (row0 + g) & (SEQ - 1);
        if (s==12 || s==36 || s==104 || s==304 || s==888 || s==2592 || s==7568)
          continue;                            // chain writes these rows
#pragma unroll
        for (int q = 0; q < 4; ++q) {
          const size_t i = base + (size_t)g*256 + q*64 + lane;
          const fx4 v = __builtin_nontemporal_load(&src4[i]);
          __builtin_nontemporal_store(v, &dst4[i]);
        }
      }
    }
  }
}

// ---------------------------------------------------------------------------
// Launch
// ---------------------------------------------------------------------------
extern "C" void kernel_launch(void* const* d_in, const int* in_sizes, int n_in,
                              void* d_out, int out_size, void* d_ws, size_t ws_size,
                              hipStream_t stream)
{
  const float* x          = (const float*)d_in[0];
  const float* lt_w1      = (const float*)d_in[1];
  const float* lt_b1      = (const float*)d_in[2];
  const float* lt_ln_g    = (const float*)d_in[3];
  const float* lt_ln_b    = (const float*)d_in[4];
  const float* lt_w2      = (const float*)d_in[5];
  const float* lt_b2      = (const float*)d_in[6];
  const float* attn_in_w  = (const float*)d_in[7];
  const float* attn_in_b  = (const float*)d_in[8];
  const float* attn_out_w = (const float*)d_in[9];
  const float* attn_out_b = (const float*)d_in[10];
  const float* fus_w      = (const float*)d_in[11];
  const float* fus_b      = (const float*)d_in[12];
  const float* fus_ln_g   = (const float*)d_in[13];
  const float* fus_ln_b   = (const float*)d_in[14];
  float* out = (float*)d_out;
  float* ws  = (float*)d_ws;

  // zero the barrier counters + copy counter (64 uints)
  (void)hipMemsetAsync(d_ws, 0, 256, stream);

  k_mega<<<NB, 256, 0, stream>>>(x, lt_w1, lt_b1, lt_ln_g, lt_ln_b, lt_w2, lt_b2,
                                 attn_in_w, attn_in_b, attn_out_w, attn_out_b,
                                 fus_w, fus_b, fus_ln_g, fus_ln_b, out, ws);
}

// Round 4
// 333.581 us; speedup vs baseline: 1.2833x; 1.2833x over previous
//
#include <hip/hip_runtime.h>
#include <math.h>

// ---------------------------------------------------------------------------
// B=4, S=8192, D=1024, H=4, hd=256.
// Static lattice: positions {12,36,104,304,888,2592,7568}; 16 entries
// (level-major: L1 E0..E6, L2 E7..E12, L3 E13..E15).
//
// ONE persistent kernel, contention-free:
//   blocks [0,256)   : 9-stage chain ordered by padded device barriers
//                      (relaxed-load spin, one RMW per block per phase),
//                      then copy their static 2-chunk share.
//   blocks [256,1024): statically copy 10 chunks each (16 KB chunks),
//                      plain loads (L3-friendly), nontemporal stores.
// No global atomics on the copy path at all.
// Co-residency: __launch_bounds__(256,4), VGPR<=128 -> 4 blocks/CU ->
// all 1024 blocks resident; copy blocks never wait -> no deadlock.
// ---------------------------------------------------------------------------

#define SEQ 8192
#define DM  1024
#define NBLK  1024
#define CHAIN 256
// 8192 chunks of 16 KB (4 rows each): 768*10 + 256*2 = 8192
#define CPB_COPY  10
#define CPB_CHAIN 2

typedef float fx4 __attribute__((ext_vector_type(4)));

__device__ __constant__ int c_nodes[16][3] = {
  {0,2,4},{2,4,12},{4,12,36},{12,36,104},{36,104,304},{104,304,888},{304,888,2592},
  {0,0,0},{0,2,0},{0,2,4},{2,4,12},{4,12,36},{12,36,104},
  {0,0,0},{0,2,0},{0,2,4}};
__device__ __constant__ float c_wt[16][3] = {
  {1,1,1},{1,1,1},{1,1,1},{1,1,1},{1,1,1},{1,1,1},{1,1,1},
  {1,0,0},{1,1,0},{1,1,1},{1,2,3},{1,2,3},{1,2,3},
  {1,0,0},{1,1,0},{1,1,1}};
__device__ __constant__ float c_winv[16] = {
  1.f/3.f,1.f/3.f,1.f/3.f,1.f/3.f,1.f/3.f,1.f/3.f,1.f/3.f,
  1.f,0.5f,1.f/3.f,1.f/6.f,1.f/6.f,1.f/6.f,
  1.f,0.5f,1.f/3.f};
__device__ __constant__ int c_pos[7]  = {12,36,104,304,888,2592,7568};
__device__ __constant__ int c_ne[7]   = {1,2,2,2,3,3,3};
__device__ __constant__ int c_posE[7][3] = {
  {0,0,0},{1,7,0},{2,8,0},{3,9,0},{4,10,13},{5,11,14},{6,12,15}};

// 8-row chunk tables for the lattice GEMMs (rows entry-major):
// L1 rows [0,28), L2 [28,52), L3 [52,64)
__device__ __constant__ int c_lr0[9]  = {0,8,16,24,28,36,44,52,60};
__device__ __constant__ int c_lnr[9]  = {8,8,8,4,8,8,8,8,4};
__device__ __constant__ int c_llv[9]  = {0,0,0,0,1,1,1,2,2};
__device__ __constant__ int c_qr0[4]  = {0,8,16,24};
__device__ __constant__ int c_qnr[4]  = {8,8,8,4};
__device__ __constant__ int c_or0[4]  = {0,8,16,24};
__device__ __constant__ int c_onr[4]  = {8,8,8,4};

// ---------------------------------------------------------------------------
// device barrier among CHAIN blocks: bar[phase] padded to 32 uints (128 B).
// Arrival: one fetch_add. Spin: relaxed atomic LOAD (no RMW) + s_sleep.
// ---------------------------------------------------------------------------
__device__ __forceinline__ void gbar(unsigned* __restrict__ bar, int phase)
{
  __syncthreads();
  if (threadIdx.x == 0) {
    unsigned* p = bar + phase * 32;
    __threadfence();   // release my stage's writes (agent scope)
    __hip_atomic_fetch_add(p, 1u, __ATOMIC_ACQ_REL, __HIP_MEMORY_SCOPE_AGENT);
    while (__hip_atomic_load(p, __ATOMIC_RELAXED, __HIP_MEMORY_SCOPE_AGENT)
           < (unsigned)CHAIN)
      __builtin_amdgcn_s_sleep(2);
    __threadfence();   // acquire other blocks' writes
  }
  __syncthreads();
}

// ---------------------------------------------------------------------------
// GEMM task: Y[r0..r0+nr)[jt*16..+16) = X(nr rows, stride K) * W^T + bias.
// 4 waves/block, wave handles 4 consecutive j; lanes over k (float4).
// ---------------------------------------------------------------------------
__device__ __forceinline__ void gemm8(const float* __restrict__ X,
                                      const float* __restrict__ W,
                                      const float* __restrict__ Bv,
                                      float* __restrict__ Y,
                                      int r0, int nr, int jt, int K, int ldy)
{
  const int lane = threadIdx.x & 63;
  const int wv   = threadIdx.x >> 6;
  const int jbase = jt * 16 + wv * 4;

  float a0[8], a1[8], a2[8], a3[8];
#pragma unroll
  for (int r = 0; r < 8; ++r) { a0[r]=0.f; a1[r]=0.f; a2[r]=0.f; a3[r]=0.f; }

  const int T = K >> 8;
  for (int t = 0; t < T; ++t) {
    const int k = t * 256 + lane * 4;
    const float4 w0 = *(const float4*)(W + (size_t)(jbase+0)*K + k);
    const float4 w1 = *(const float4*)(W + (size_t)(jbase+1)*K + k);
    const float4 w2 = *(const float4*)(W + (size_t)(jbase+2)*K + k);
    const float4 w3 = *(const float4*)(W + (size_t)(jbase+3)*K + k);
#pragma unroll
    for (int r = 0; r < 8; ++r) {
      const int rr = (r < nr) ? r : (nr - 1);
      const float4 xv = *(const float4*)(X + (size_t)(r0+rr)*K + k);
      a0[r] += w0.x*xv.x + w0.y*xv.y + w0.z*xv.z + w0.w*xv.w;
      a1[r] += w1.x*xv.x + w1.y*xv.y + w1.z*xv.z + w1.w*xv.w;
      a2[r] += w2.x*xv.x + w2.y*xv.y + w2.z*xv.z + w2.w*xv.w;
      a3[r] += w3.x*xv.x + w3.y*xv.y + w3.z*xv.z + w3.w*xv.w;
    }
  }
#pragma unroll
  for (int r = 0; r < 8; ++r) {
    float v0 = a0[r], v1 = a1[r], v2 = a2[r], v3 = a3[r];
#pragma unroll
    for (int off = 32; off >= 1; off >>= 1) {
      v0 += __shfl_xor(v0, off); v1 += __shfl_xor(v1, off);
      v2 += __shfl_xor(v2, off); v3 += __shfl_xor(v3, off);
    }
    a0[r] = v0; a1[r] = v1; a2[r] = v2; a3[r] = v3;
  }
  if (lane == 0) {
    const float b0 = Bv[jbase+0], b1 = Bv[jbase+1];
    const float b2 = Bv[jbase+2], b3 = Bv[jbase+3];
#pragma unroll
    for (int r = 0; r < 8; ++r) {
      if (r < nr) {
        float* yr = Y + (size_t)(r0+r)*ldy + jbase;
        yr[0] = a0[r]+b0; yr[1] = a1[r]+b1; yr[2] = a2[r]+b2; yr[3] = a3[r]+b3;
      }
    }
  }
}

// block mean/rstd over one 1024-row (256 threads x 4 elems)
__device__ __forceinline__ void block_mv(float s, float q, float* mean, float* rstd)
{
  __shared__ float s1[4], s2[4];
  const int lane = threadIdx.x & 63, wv = threadIdx.x >> 6;
#pragma unroll
  for (int off = 32; off >= 1; off >>= 1) {
    s += __shfl_xor(s, off); q += __shfl_xor(q, off);
  }
  if (lane == 0) { s1[wv] = s; s2[wv] = q; }
  __syncthreads();
  const float ts = s1[0]+s1[1]+s1[2]+s1[3];
  const float tq = s2[0]+s2[1]+s2[2]+s2[3];
  const float m = ts * (1.f/1024.f);
  *mean = m;
  *rstd = rsqrtf(tq * (1.f/1024.f) - m*m + 1e-5f);
}

// copy n chunks starting at c0: 16 KB each (4 rows of 1024 floats);
// plain loads (keep x in L3), nontemporal stores (don't pollute L3).
__device__ __forceinline__ void copy_chunks(const float* __restrict__ x,
                                            float* __restrict__ out,
                                            int c0, int n)
{
  const fx4* __restrict__ src4 = (const fx4*)x;
  fx4* __restrict__ dst4 = (fx4*)out;
  for (int c = c0; c < c0 + n; ++c) {
    const size_t base = (size_t)c * 1024;
#pragma unroll
    for (int k = 0; k < 4; ++k) {
      const int s = (c * 4 + k) & (SEQ - 1);
      if (s==12 || s==36 || s==104 || s==304 || s==888 || s==2592 || s==7568)
        continue;                          // chain writes these rows
      const size_t i = base + (size_t)k * 256 + threadIdx.x;
      const fx4 v = src4[i];
      __builtin_nontemporal_store(v, &dst4[i]);
    }
  }
}

// ---------------------------------------------------------------------------
// The mega kernel
// ---------------------------------------------------------------------------
__global__ __launch_bounds__(256, 4)
void k_mega(const float* __restrict__ x,
            const float* __restrict__ lt_w1, const float* __restrict__ lt_b1,
            const float* __restrict__ lt_ln_g, const float* __restrict__ lt_ln_b,
            const float* __restrict__ lt_w2, const float* __restrict__ lt_b2,
            const float* __restrict__ attn_in_w, const float* __restrict__ attn_in_b,
            const float* __restrict__ attn_out_w, const float* __restrict__ attn_out_b,
            const float* __restrict__ fus_w, const float* __restrict__ fus_b,
            const float* __restrict__ fus_ln_g, const float* __restrict__ fus_ln_b,
            float* __restrict__ out, float* __restrict__ ws)
{
  unsigned* bar = (unsigned*)ws;          // 8 phases x 32 uints (128 B apart)
  float* F   = ws + 256;                  // 64 x 1024
  float* Hh  = F   + 65536;               // 64 x 1024
  float* KV  = Hh  + 65536;               // 64 x 1024
  float* QIN = KV  + 65536;               // 32 x 1024 (28 valid)
  float* QH  = QIN + 32768;               // 32 x 1024
  float* KH  = QH  + 32768;               // 64 x 1024
  float* VH  = KH  + 65536;               // 64 x 1024
  float* OA  = VH  + 65536;               // 32 x 1024
  float* CB  = OA  + 32768;               // 32 x 2048  ([o | q])
  float* UP  = CB  + 65536;               // 32 x 1024

  const int cb = blockIdx.x;

  if (cb >= CHAIN) {
    // ---- pure copy block: static 10-chunk share -----------------------
    copy_chunks(x, out, (cb - CHAIN) * CPB_COPY, CPB_COPY);
    return;
  }

  // ======================= chain blocks [0,256) ========================
  // ---- S0: lattice feature means + gather q rows ----------------------
  for (int task = cb; task < 92; task += CHAIN) {
    const int d = threadIdx.x * 4;
    if (task < 64) {
      const int e = task >> 2, b = task & 3;
      float4 s = make_float4(0.f,0.f,0.f,0.f);
#pragma unroll
      for (int n = 0; n < 3; ++n) {
        const float w = c_wt[e][n];
        const float4 v = *(const float4*)(x + ((size_t)b*SEQ + c_nodes[e][n])*DM + d);
        s.x += w*v.x; s.y += w*v.y; s.z += w*v.z; s.w += w*v.w;
      }
      const float inv = c_winv[e];
      s.x*=inv; s.y*=inv; s.z*=inv; s.w*=inv;
      *(float4*)(F + (size_t)(e*4+b)*DM + d) = s;
    } else {
      const int i = task - 64;            // 0..27
      const int p = i >> 2, b = i & 3;
      const float4 v = *(const float4*)(x + ((size_t)b*SEQ + c_pos[p])*DM + d);
      *(float4*)(QIN + (size_t)i*DM + d) = v;
      *(float4*)(CB + (size_t)i*2048 + 1024 + d) = v;
    }
  }
  gbar(bar, 0);

  // ---- S1: H = F @ lt_w1^T + b1 (per level) ---------------------------
  for (int task = cb; task < 576; task += CHAIN) {
    const int ch = task >> 6, jt = task & 63;
    const int lvl = c_llv[ch];
    gemm8(F, lt_w1 + (size_t)lvl*DM*DM, lt_b1 + lvl*DM, Hh,
          c_lr0[ch], c_lnr[ch], jt, DM, DM);
  }
  gbar(bar, 1);

  // ---- S2: LN + exact GELU in place on Hh -----------------------------
  for (int row = cb; row < 64; row += CHAIN) {
    const int e = row >> 2;
    const int lvl = (e < 7) ? 0 : ((e < 13) ? 1 : 2);
    const int j = threadIdx.x * 4;
    float* hr = Hh + (size_t)row*DM + j;
    float4 v = *(float4*)hr;
    float mean, rstd;
    block_mv(v.x+v.y+v.z+v.w, v.x*v.x+v.y*v.y+v.z*v.z+v.w*v.w, &mean, &rstd);
    const float* gg = lt_ln_g + lvl*DM + j;
    const float* bb = lt_ln_b + lvl*DM + j;
    const float t0 = (v.x-mean)*rstd*gg[0] + bb[0];
    const float t1 = (v.y-mean)*rstd*gg[1] + bb[1];
    const float t2 = (v.z-mean)*rstd*gg[2] + bb[2];
    const float t3 = (v.w-mean)*rstd*gg[3] + bb[3];
    const float kc = 0.70710678118654752f;
    v.x = 0.5f*t0*(1.f+erff(t0*kc));
    v.y = 0.5f*t1*(1.f+erff(t1*kc));
    v.z = 0.5f*t2*(1.f+erff(t2*kc));
    v.w = 0.5f*t3*(1.f+erff(t3*kc));
    *(float4*)hr = v;
  }
  gbar(bar, 2);

  // ---- S3: KV = H @ lt_w2^T + b2 --------------------------------------
  for (int task = cb; task < 576; task += CHAIN) {
    const int ch = task >> 6, jt = task & 63;
    const int lvl = c_llv[ch];
    gemm8(Hh, lt_w2 + (size_t)lvl*DM*DM, lt_b2 + lvl*DM, KV,
          c_lr0[ch], c_lnr[ch], jt, DM, DM);
  }
  gbar(bar, 3);

  // ---- S4: Q/K/V projections ------------------------------------------
  for (int task = cb; task < 1280; task += CHAIN) {
    const int ch = task >> 6, jt = task & 63;
    if (ch < 4)
      gemm8(QIN, attn_in_w, attn_in_b, QH, c_qr0[ch], c_qnr[ch], jt, DM, DM);
    else if (ch < 12)
      gemm8(KV, attn_in_w + (size_t)DM*DM, attn_in_b + DM, KH,
            (ch-4)*8, 8, jt, DM, DM);
    else
      gemm8(KV, attn_in_w + (size_t)2*DM*DM, attn_in_b + 2*DM, VH,
            (ch-12)*8, 8, jt, DM, DM);
  }
  gbar(bar, 4);

  // ---- S5: attention (block = (p,b), wave = head) ---------------------
  for (int task = cb; task < 28; task += CHAIN) {
    const int p = task >> 2, b = task & 3;
    const int h = threadIdx.x >> 6, lane = threadIdx.x & 63;
    const int ne = c_ne[p];
    const int qoff = (p*4+b)*DM + h*256 + lane;
    const float q0 = QH[qoff], q1 = QH[qoff+64], q2 = QH[qoff+128], q3 = QH[qoff+192];
    float sc0 = -1e30f, sc1 = -1e30f, sc2 = -1e30f;
    int k0 = 0, k1 = 0, k2 = 0;
    {
      k0 = (c_posE[p][0]*4 + b)*DM + h*256 + lane;
      float pr = q0*KH[k0] + q1*KH[k0+64] + q2*KH[k0+128] + q3*KH[k0+192];
#pragma unroll
      for (int off = 32; off >= 1; off >>= 1) pr += __shfl_xor(pr, off);
      sc0 = pr * 0.0625f;
    }
    if (ne > 1) {
      k1 = (c_posE[p][1]*4 + b)*DM + h*256 + lane;
      float pr = q0*KH[k1] + q1*KH[k1+64] + q2*KH[k1+128] + q3*KH[k1+192];
#pragma unroll
      for (int off = 32; off >= 1; off >>= 1) pr += __shfl_xor(pr, off);
      sc1 = pr * 0.0625f;
    }
    if (ne > 2) {
      k2 = (c_posE[p][2]*4 + b)*DM + h*256 + lane;
      float pr = q0*KH[k2] + q1*KH[k2+64] + q2*KH[k2+128] + q3*KH[k2+192];
#pragma unroll
      for (int off = 32; off >= 1; off >>= 1) pr += __shfl_xor(pr, off);
      sc2 = pr * 0.0625f;
    }
    const float m = fmaxf(sc0, fmaxf(sc1, sc2));
    const float e0 = expf(sc0 - m);
    const float e1 = (ne > 1) ? expf(sc1 - m) : 0.f;
    const float e2 = (ne > 2) ? expf(sc2 - m) : 0.f;
    const float inv = 1.f / (e0+e1+e2);
    const float A0 = e0*inv, A1 = e1*inv, A2 = e2*inv;
#pragma unroll
    for (int i = 0; i < 4; ++i) {
      float o = A0 * VH[k0 + i*64];
      if (ne > 1) o += A1 * VH[k1 + i*64];
      if (ne > 2) o += A2 * VH[k2 + i*64];
      OA[qoff + i*64] = o;
    }
  }
  gbar(bar, 5);

  // ---- S6: out-projection into CB[:, 0:1024) --------------------------
  for (int task = cb; task < 256; task += CHAIN) {
    const int ch = task >> 6, jt = task & 63;
    gemm8(OA, attn_out_w, attn_out_b, CB, c_or0[ch], c_onr[ch], jt, DM, 2048);
  }
  gbar(bar, 6);

  // ---- S7: fusion GEMM (K = 2048) -------------------------------------
  for (int task = cb; task < 256; task += CHAIN) {
    const int ch = task >> 6, jt = task & 63;
    gemm8(CB, fus_w, fus_b, UP, c_or0[ch], c_onr[ch], jt, 2048, DM);
  }
  gbar(bar, 7);

  // ---- S8: final LN + scatter 28 rows into out ------------------------
  for (int row = cb; row < 28; row += CHAIN) {
    const int p = row >> 2, b = row & 3;
    const int j = threadIdx.x * 4;
    const float4 v = *(const float4*)(UP + (size_t)row*DM + j);
    float mean, rstd;
    block_mv(v.x+v.y+v.z+v.w, v.x*v.x+v.y*v.y+v.z*v.z+v.w*v.w, &mean, &rstd);
    const float* gg = fus_ln_g + j;
    const float* bb = fus_ln_b + j;
    float4 o;
    o.x = (v.x-mean)*rstd*gg[0] + bb[0];
    o.y = (v.y-mean)*rstd*gg[1] + bb[1];
    o.z = (v.z-mean)*rstd*gg[2] + bb[2];
    o.w = (v.w-mean)*rstd*gg[3] + bb[3];
    *(float4*)(out + ((size_t)b*SEQ + c_pos[p])*DM + j) = o;
  }

  // ---- chain block's static copy share (no barrier needed) ------------
  copy_chunks(x, out, 768 * CPB_COPY + cb * CPB_CHAIN, CPB_CHAIN);
}

// ---------------------------------------------------------------------------
// Launch
// ---------------------------------------------------------------------------
extern "C" void kernel_launch(void* const* d_in, const int* in_sizes, int n_in,
                              void* d_out, int out_size, void* d_ws, size_t ws_size,
                              hipStream_t stream)
{
  const float* x          = (const float*)d_in[0];
  const float* lt_w1      = (const float*)d_in[1];
  const float* lt_b1      = (const float*)d_in[2];
  const float* lt_ln_g    = (const float*)d_in[3];
  const float* lt_ln_b    = (const float*)d_in[4];
  const float* lt_w2      = (const float*)d_in[5];
  const float* lt_b2      = (const float*)d_in[6];
  const float* attn_in_w  = (const float*)d_in[7];
  const float* attn_in_b  = (const float*)d_in[8];
  const float* attn_out_w = (const float*)d_in[9];
  const float* attn_out_b = (const float*)d_in[10];
  const float* fus_w      = (const float*)d_in[11];
  const float* fus_b      = (const float*)d_in[12];
  const float* fus_ln_g   = (const float*)d_in[13];
  const float* fus_ln_b   = (const float*)d_in[14];
  float* out = (float*)d_out;
  float* ws  = (float*)d_ws;

  // zero the 8 padded barrier counters (8 x 128 B)
  (void)hipMemsetAsync(d_ws, 0, 1024, stream);

  k_mega<<<NBLK, 256, 0, stream>>>(x, lt_w1, lt_b1, lt_ln_g, lt_ln_b, lt_w2, lt_b2,
                                   attn_in_w, attn_in_b, attn_out_w, attn_out_b,
                                   fus_w, fus_b, fus_ln_g, fus_ln_b, out, ws);
}

// Round 5
// 312.601 us; speedup vs baseline: 1.3695x; 1.0671x over previous
//
#include <hip/hip_runtime.h>
#include <math.h>

// ---------------------------------------------------------------------------
// B=4, S=8192, D=1024, H=4, hd=256.
// Static lattice: positions {12,36,104,304,888,2592,7568}; 16 entries
// (level-major: L1 E0..E6, L2 E7..E12, L3 E13..E15).
//
// 7 kernels, HW-synced via stream order (no device barriers / fences /
// atomics). Every kernel's surplus blocks copy a static slice of x->out
// (plain loads: keep x L3-resident; nontemporal stores: don't evict it).
//   K2: F rows built in LDS per task -> H = F@W1^T+b1
//   K3: LN+GELU(H) staged in LDS per task -> KV = .@W2^T+b2
//   K4: Q/K/V projections (Q rows gathered straight from x)
//   K5: attention (28 blocks)
//   K6: out-projection -> O
//   K7: fusion GEMM K=2048 ([O | x-rows])
//   K8: final LN + scatter 28 rows
// ---------------------------------------------------------------------------

#define SEQ 8192
#define DM  1024

// copy chunk bases (16 KB chunks of the 128 MB buffer; 8192 total)
#define K2BASE 0
#define K3BASE 1200
#define K4BASE 2400
#define K5BASE 3800
#define K6BASE 5200
#define K7BASE 6600
#define K8BASE 8000

typedef float fx4 __attribute__((ext_vector_type(4)));

__device__ __constant__ int c_nodes[16][3] = {
  {0,2,4},{2,4,12},{4,12,36},{12,36,104},{36,104,304},{104,304,888},{304,888,2592},
  {0,0,0},{0,2,0},{0,2,4},{2,4,12},{4,12,36},{12,36,104},
  {0,0,0},{0,2,0},{0,2,4}};
__device__ __constant__ float c_wt[16][3] = {
  {1,1,1},{1,1,1},{1,1,1},{1,1,1},{1,1,1},{1,1,1},{1,1,1},
  {1,0,0},{1,1,0},{1,1,1},{1,2,3},{1,2,3},{1,2,3},
  {1,0,0},{1,1,0},{1,1,1}};
__device__ __constant__ float c_winv[16] = {
  1.f/3.f,1.f/3.f,1.f/3.f,1.f/3.f,1.f/3.f,1.f/3.f,1.f/3.f,
  1.f,0.5f,1.f/3.f,1.f/6.f,1.f/6.f,1.f/6.f,
  1.f,0.5f,1.f/3.f};
__device__ __constant__ int c_pos[7]  = {12,36,104,304,888,2592,7568};
__device__ __constant__ int c_ne[7]   = {1,2,2,2,3,3,3};
__device__ __constant__ int c_posE[7][3] = {
  {0,0,0},{1,7,0},{2,8,0},{3,9,0},{4,10,13},{5,11,14},{6,12,15}};

// 8-row chunks of the 64 entry-rows (levels don't cross chunks)
__device__ __constant__ int c_lr0[9]  = {0,8,16,24,28,36,44,52,60};
__device__ __constant__ int c_lnr[9]  = {8,8,8,4,8,8,8,8,4};
__device__ __constant__ int c_llv[9]  = {0,0,0,0,1,1,1,2,2};
__device__ __constant__ int c_or0[4]  = {0,8,16,24};
__device__ __constant__ int c_onr[4]  = {8,8,8,4};

// ---------------------------------------------------------------------------
// copy n 16KB-chunks (4 rows each) starting at c0; skip the 28 updated rows.
// ---------------------------------------------------------------------------
__device__ __forceinline__ void copy_chunks(const float* __restrict__ x,
                                            float* __restrict__ out,
                                            int c0, int n)
{
  const fx4* __restrict__ src4 = (const fx4*)x;
  fx4* __restrict__ dst4 = (fx4*)out;
  for (int c = c0; c < c0 + n; ++c) {
    const size_t base = (size_t)c * 1024;
#pragma unroll
    for (int k = 0; k < 4; ++k) {
      const int s = (c * 4 + k) & (SEQ - 1);
      if (s==12 || s==36 || s==104 || s==304 || s==888 || s==2592 || s==7568)
        continue;
      const size_t i = base + (size_t)k * 256 + threadIdx.x;
      const fx4 v = src4[i];
      __builtin_nontemporal_store(v, &dst4[i]);
    }
  }
}

// ---------------------------------------------------------------------------
// GEMM cores: 4 waves/block, wave wv owns j = jbase..jbase+3; lanes over k.
// A[4][8] accumulates 4 j x 8 rows; butterfly-reduce at the end.
// ---------------------------------------------------------------------------
template<int TITER>
__device__ __forceinline__ void gemm_acc_g(const float* const* Xr,
                                           const float* __restrict__ W,
                                           int Wld, int k0, int jbase,
                                           float (&A)[4][8])
{
  const int lane = threadIdx.x & 63;
#pragma unroll
  for (int t = 0; t < TITER; ++t) {
    const int kx = t * 256 + lane * 4;
    const float* wp = W + (size_t)jbase * Wld + k0 + kx;
    const float4 w0 = *(const float4*)(wp);
    const float4 w1 = *(const float4*)(wp + Wld);
    const float4 w2 = *(const float4*)(wp + 2 * Wld);
    const float4 w3 = *(const float4*)(wp + 3 * Wld);
#pragma unroll
    for (int r = 0; r < 8; ++r) {
      const float4 xv = *(const float4*)(Xr[r] + kx);
      A[0][r] += w0.x*xv.x + w0.y*xv.y + w0.z*xv.z + w0.w*xv.w;
      A[1][r] += w1.x*xv.x + w1.y*xv.y + w1.z*xv.z + w1.w*xv.w;
      A[2][r] += w2.x*xv.x + w2.y*xv.y + w2.z*xv.z + w2.w*xv.w;
      A[3][r] += w3.x*xv.x + w3.y*xv.y + w3.z*xv.z + w3.w*xv.w;
    }
  }
}

template<int TITER>
__device__ __forceinline__ void gemm_acc_s(const float (*Xs)[1024], int nr,
                                           const float* __restrict__ W,
                                           int Wld, int jbase, float (&A)[4][8])
{
  const int lane = threadIdx.x & 63;
#pragma unroll
  for (int t = 0; t < TITER; ++t) {
    const int kx = t * 256 + lane * 4;
    const float* wp = W + (size_t)jbase * Wld + kx;
    const float4 w0 = *(const float4*)(wp);
    const float4 w1 = *(const float4*)(wp + Wld);
    const float4 w2 = *(const float4*)(wp + 2 * Wld);
    const float4 w3 = *(const float4*)(wp + 3 * Wld);
#pragma unroll
    for (int r = 0; r < 8; ++r) {
      const int rc = (r < nr) ? r : nr - 1;
      const float4 xv = *(const float4*)(&Xs[rc][kx]);
      A[0][r] += w0.x*xv.x + w0.y*xv.y + w0.z*xv.z + w0.w*xv.w;
      A[1][r] += w1.x*xv.x + w1.y*xv.y + w1.z*xv.z + w1.w*xv.w;
      A[2][r] += w2.x*xv.x + w2.y*xv.y + w2.z*xv.z + w2.w*xv.w;
      A[3][r] += w3.x*xv.x + w3.y*xv.y + w3.z*xv.z + w3.w*xv.w;
    }
  }
}

__device__ __forceinline__ void gemm_fin(float (&A)[4][8],
                                         const float* __restrict__ Bv,
                                         int jbase, float* __restrict__ Y,
                                         int r0, int nr, int ldy)
{
  const int lane = threadIdx.x & 63;
#pragma unroll
  for (int r = 0; r < 8; ++r) {
    float v0 = A[0][r], v1 = A[1][r], v2 = A[2][r], v3 = A[3][r];
#pragma unroll
    for (int off = 32; off >= 1; off >>= 1) {
      v0 += __shfl_xor(v0, off); v1 += __shfl_xor(v1, off);
      v2 += __shfl_xor(v2, off); v3 += __shfl_xor(v3, off);
    }
    if (lane == 0 && r < nr) {
      float* yr = Y + (size_t)(r0 + r) * ldy + jbase;
      yr[0] = v0 + Bv[jbase + 0]; yr[1] = v1 + Bv[jbase + 1];
      yr[2] = v2 + Bv[jbase + 2]; yr[3] = v3 + Bv[jbase + 3];
    }
  }
}

// block mean/rstd over a 1024-row (256 threads x 4), safe for repeated use
__device__ __forceinline__ void block_mv(float s, float q, float* mean, float* rstd)
{
  __shared__ float s1[4], s2[4];
  const int lane = threadIdx.x & 63, wv = threadIdx.x >> 6;
#pragma unroll
  for (int off = 32; off >= 1; off >>= 1) {
    s += __shfl_xor(s, off); q += __shfl_xor(q, off);
  }
  if (lane == 0) { s1[wv] = s; s2[wv] = q; }
  __syncthreads();
  const float ts = s1[0]+s1[1]+s1[2]+s1[3];
  const float tq = s2[0]+s2[1]+s2[2]+s2[3];
  const float m = ts * (1.f/1024.f);
  *mean = m;
  *rstd = rsqrtf(tq * (1.f/1024.f) - m*m + 1e-5f);
  __syncthreads();   // protect s1/s2 for the next call
}

// ---------------------------------------------------------------------------
// K2: stage F rows in LDS, H = F @ lt_w1^T + b1
// ---------------------------------------------------------------------------
__global__ __launch_bounds__(256, 4)
void k_lat1(const float* __restrict__ x, const float* __restrict__ w1,
            const float* __restrict__ b1, float* __restrict__ Hh,
            float* __restrict__ out)
{
  const int bid = blockIdx.x;
  if (bid >= 576) { copy_chunks(x, out, K2BASE + (bid - 576) * 2, 2); return; }
  const int ch = bid >> 6, jt = bid & 63;
  const int r0 = c_lr0[ch], nr = c_lnr[ch], lvl = c_llv[ch];
  const int tid = threadIdx.x;
  __shared__ float Xs[8][1024];
  for (int rr = 0; rr < nr; ++rr) {
    const int row = r0 + rr, e = row >> 2, b = row & 3;
    float4 s = make_float4(0.f, 0.f, 0.f, 0.f);
#pragma unroll
    for (int n = 0; n < 3; ++n) {
      const float w = c_wt[e][n];
      const float4 v = *(const float4*)(x + ((size_t)b*SEQ + c_nodes[e][n])*DM + tid*4);
      s.x += w*v.x; s.y += w*v.y; s.z += w*v.z; s.w += w*v.w;
    }
    const float inv = c_winv[e];
    *(float4*)&Xs[rr][tid*4] = make_float4(s.x*inv, s.y*inv, s.z*inv, s.w*inv);
  }
  __syncthreads();
  const int jbase = jt * 16 + (tid >> 6) * 4;
  float A[4][8] = {};
  gemm_acc_s<4>(Xs, nr, w1 + (size_t)lvl*DM*DM, DM, jbase, A);
  gemm_fin(A, b1 + lvl*DM, jbase, Hh, r0, nr, DM);
}

// ---------------------------------------------------------------------------
// K3: stage LN+GELU(H) rows in LDS, KV = . @ lt_w2^T + b2
// ---------------------------------------------------------------------------
__global__ __launch_bounds__(256, 4)
void k_lat2(const float* __restrict__ x, const float* __restrict__ Hh,
            const float* __restrict__ ln_g, const float* __restrict__ ln_b,
            const float* __restrict__ w2, const float* __restrict__ b2,
            float* __restrict__ KV, float* __restrict__ out)
{
  const int bid = blockIdx.x;
  if (bid >= 576) { copy_chunks(x, out, K3BASE + (bid - 576) * 2, 2); return; }
  const int ch = bid >> 6, jt = bid & 63;
  const int r0 = c_lr0[ch], nr = c_lnr[ch], lvl = c_llv[ch];
  const int tid = threadIdx.x;
  __shared__ float Xs[8][1024];
  const float4 g4 = *(const float4*)(ln_g + (size_t)lvl*DM + tid*4);
  const float4 b4 = *(const float4*)(ln_b + (size_t)lvl*DM + tid*4);
  for (int rr = 0; rr < nr; ++rr) {
    const float4 v = *(const float4*)(Hh + (size_t)(r0+rr)*DM + tid*4);
    float mean, rstd;
    block_mv(v.x+v.y+v.z+v.w, v.x*v.x+v.y*v.y+v.z*v.z+v.w*v.w, &mean, &rstd);
    const float t0 = (v.x-mean)*rstd*g4.x + b4.x;
    const float t1 = (v.y-mean)*rstd*g4.y + b4.y;
    const float t2 = (v.z-mean)*rstd*g4.z + b4.z;
    const float t3 = (v.w-mean)*rstd*g4.w + b4.w;
    const float kc = 0.70710678118654752f;
    float4 o;
    o.x = 0.5f*t0*(1.f+erff(t0*kc));
    o.y = 0.5f*t1*(1.f+erff(t1*kc));
    o.z = 0.5f*t2*(1.f+erff(t2*kc));
    o.w = 0.5f*t3*(1.f+erff(t3*kc));
    *(float4*)&Xs[rr][tid*4] = o;
  }
  __syncthreads();
  const int jbase = jt * 16 + (tid >> 6) * 4;
  float A[4][8] = {};
  gemm_acc_s<4>(Xs, nr, w2 + (size_t)lvl*DM*DM, DM, jbase, A);
  gemm_fin(A, b2 + lvl*DM, jbase, KV, r0, nr, DM);
}

// ---------------------------------------------------------------------------
// K4: Q/K/V projections. Q rows gathered straight from x.
// ---------------------------------------------------------------------------
__global__ __launch_bounds__(256, 4)
void k_qkv(const float* __restrict__ x, const float* __restrict__ KV,
           const float* __restrict__ Wi, const float* __restrict__ Bi,
           float* __restrict__ QH, float* __restrict__ KH,
           float* __restrict__ VH, float* __restrict__ out)
{
  const int bid = blockIdx.x;
  if (bid >= 1280) { copy_chunks(x, out, K4BASE + (bid - 1280) * 2, 2); return; }
  const int ch = bid >> 6, jt = bid & 63;
  const int jbase = jt * 16 + (threadIdx.x >> 6) * 4;
  float A[4][8] = {};
  const float* Xr[8];
  if (ch < 4) {
    const int r0 = c_or0[ch], nr = c_onr[ch];
#pragma unroll
    for (int r = 0; r < 8; ++r) {
      const int i = r0 + ((r < nr) ? r : nr - 1);
      const int p = i >> 2, b = i & 3;
      Xr[r] = x + ((size_t)b*SEQ + c_pos[p])*DM;
    }
    gemm_acc_g<4>(Xr, Wi, DM, 0, jbase, A);
    gemm_fin(A, Bi, jbase, QH, r0, nr, DM);
  } else if (ch < 12) {
    const int r0 = (ch - 4) * 8;
#pragma unroll
    for (int r = 0; r < 8; ++r) Xr[r] = KV + (size_t)(r0 + r)*DM;
    gemm_acc_g<4>(Xr, Wi + (size_t)DM*DM, DM, 0, jbase, A);
    gemm_fin(A, Bi + DM, jbase, KH, r0, 8, DM);
  } else {
    const int r0 = (ch - 12) * 8;
#pragma unroll
    for (int r = 0; r < 8; ++r) Xr[r] = KV + (size_t)(r0 + r)*DM;
    gemm_acc_g<4>(Xr, Wi + (size_t)2*DM*DM, DM, 0, jbase, A);
    gemm_fin(A, Bi + 2*DM, jbase, VH, r0, 8, DM);
  }
}

// ---------------------------------------------------------------------------
// K5: attention. Block = (p,b), wave = head.
// ---------------------------------------------------------------------------
__global__ __launch_bounds__(256, 4)
void k_attn(const float* __restrict__ x, const float* __restrict__ QH,
            const float* __restrict__ KH, const float* __restrict__ VH,
            float* __restrict__ OA, float* __restrict__ out)
{
  const int bid = blockIdx.x;
  if (bid >= 28) { copy_chunks(x, out, K5BASE + (bid - 28) * 2, 2); return; }
  const int p = bid >> 2, b = bid & 3;
  const int h = threadIdx.x >> 6, lane = threadIdx.x & 63;
  const int ne = c_ne[p];
  const int qoff = (p*4+b)*DM + h*256 + lane;
  const float q0 = QH[qoff], q1 = QH[qoff+64], q2 = QH[qoff+128], q3 = QH[qoff+192];
  float sc0 = -1e30f, sc1 = -1e30f, sc2 = -1e30f;
  int k0 = 0, k1 = 0, k2 = 0;
  {
    k0 = (c_posE[p][0]*4 + b)*DM + h*256 + lane;
    float pr = q0*KH[k0] + q1*KH[k0+64] + q2*KH[k0+128] + q3*KH[k0+192];
#pragma unroll
    for (int off = 32; off >= 1; off >>= 1) pr += __shfl_xor(pr, off);
    sc0 = pr * 0.0625f;
  }
  if (ne > 1) {
    k1 = (c_posE[p][1]*4 + b)*DM + h*256 + lane;
    float pr = q0*KH[k1] + q1*KH[k1+64] + q2*KH[k1+128] + q3*KH[k1+192];
#pragma unroll
    for (int off = 32; off >= 1; off >>= 1) pr += __shfl_xor(pr, off);
    sc1 = pr * 0.0625f;
  }
  if (ne > 2) {
    k2 = (c_posE[p][2]*4 + b)*DM + h*256 + lane;
    float pr = q0*KH[k2] + q1*KH[k2+64] + q2*KH[k2+128] + q3*KH[k2+192];
#pragma unroll
    for (int off = 32; off >= 1; off >>= 1) pr += __shfl_xor(pr, off);
    sc2 = pr * 0.0625f;
  }
  const float m = fmaxf(sc0, fmaxf(sc1, sc2));
  const float e0 = expf(sc0 - m);
  const float e1 = (ne > 1) ? expf(sc1 - m) : 0.f;
  const float e2 = (ne > 2) ? expf(sc2 - m) : 0.f;
  const float inv = 1.f / (e0 + e1 + e2);
  const float A0 = e0*inv, A1 = e1*inv, A2 = e2*inv;
#pragma unroll
  for (int i = 0; i < 4; ++i) {
    float o = A0 * VH[k0 + i*64];
    if (ne > 1) o += A1 * VH[k1 + i*64];
    if (ne > 2) o += A2 * VH[k2 + i*64];
    OA[qoff + i*64] = o;
  }
}

// ---------------------------------------------------------------------------
// K6: out-projection O = OA @ attn_out_w^T + b
// ---------------------------------------------------------------------------
__global__ __launch_bounds__(256, 4)
void k_oproj(const float* __restrict__ x, const float* __restrict__ OA,
             const float* __restrict__ Wo, const float* __restrict__ Bo,
             float* __restrict__ O, float* __restrict__ out)
{
  const int bid = blockIdx.x;
  if (bid >= 256) { copy_chunks(x, out, K6BASE + (bid - 256) * 2, 2); return; }
  const int ch = bid >> 6, jt = bid & 63;
  const int r0 = c_or0[ch], nr = c_onr[ch];
  const int jbase = jt * 16 + (threadIdx.x >> 6) * 4;
  float A[4][8] = {};
  const float* Xr[8];
#pragma unroll
  for (int r = 0; r < 8; ++r)
    Xr[r] = OA + (size_t)(r0 + ((r < nr) ? r : nr - 1))*DM;
  gemm_acc_g<4>(Xr, Wo, DM, 0, jbase, A);
  gemm_fin(A, Bo, jbase, O, r0, nr, DM);
}

// ---------------------------------------------------------------------------
// K7: fusion GEMM, K=2048 over [O | x-rows]
// ---------------------------------------------------------------------------
__global__ __launch_bounds__(256, 4)
void k_fus(const float* __restrict__ x, const float* __restrict__ O,
           const float* __restrict__ Wf, const float* __restrict__ Bf,
           float* __restrict__ UP, float* __restrict__ out)
{
  const int bid = blockIdx.x;
  if (bid >= 256) { copy_chunks(x, out, K7BASE + (bid - 256) * 2, 2); return; }
  const int ch = bid >> 6, jt = bid & 63;
  const int r0 = c_or0[ch], nr = c_onr[ch];
  const int jbase = jt * 16 + (threadIdx.x >> 6) * 4;
  float A[4][8] = {};
  const float* XrO[8]; const float* XrX[8];
#pragma unroll
  for (int r = 0; r < 8; ++r) {
    const int i = r0 + ((r < nr) ? r : nr - 1);
    const int p = i >> 2, b = i & 3;
    XrO[r] = O + (size_t)i*DM;
    XrX[r] = x + ((size_t)b*SEQ + c_pos[p])*DM;
  }
  gemm_acc_g<4>(XrO, Wf, 2048, 0, jbase, A);
  gemm_acc_g<4>(XrX, Wf, 2048, 1024, jbase, A);
  gemm_fin(A, Bf, jbase, UP, r0, nr, DM);
}

// ---------------------------------------------------------------------------
// K8: final LN + scatter the 28 updated rows
// ---------------------------------------------------------------------------
__global__ __launch_bounds__(256, 4)
void k_final(const float* __restrict__ x, const float* __restrict__ UP,
             const float* __restrict__ g, const float* __restrict__ bt,
             float* __restrict__ out)
{
  const int bid = blockIdx.x;
  if (bid >= 28) { copy_chunks(x, out, K8BASE + (bid - 28) * 2, 2); return; }
  const int p = bid >> 2, b = bid & 3;
  const int j = threadIdx.x * 4;
  const float4 v = *(const float4*)(UP + (size_t)bid*DM + j);
  float mean, rstd;
  block_mv(v.x+v.y+v.z+v.w, v.x*v.x+v.y*v.y+v.z*v.z+v.w*v.w, &mean, &rstd);
  const float* gg = g + j;
  const float* bb = bt + j;
  float4 o;
  o.x = (v.x-mean)*rstd*gg[0] + bb[0];
  o.y = (v.y-mean)*rstd*gg[1] + bb[1];
  o.z = (v.z-mean)*rstd*gg[2] + bb[2];
  o.w = (v.w-mean)*rstd*gg[3] + bb[3];
  *(float4*)(out + ((size_t)b*SEQ + c_pos[p])*DM + j) = o;
}

// ---------------------------------------------------------------------------
// Launch
// ---------------------------------------------------------------------------
extern "C" void kernel_launch(void* const* d_in, const int* in_sizes, int n_in,
                              void* d_out, int out_size, void* d_ws, size_t ws_size,
                              hipStream_t stream)
{
  const float* x          = (const float*)d_in[0];
  const float* lt_w1      = (const float*)d_in[1];
  const float* lt_b1      = (const float*)d_in[2];
  const float* lt_ln_g    = (const float*)d_in[3];
  const float* lt_ln_b    = (const float*)d_in[4];
  const float* lt_w2      = (const float*)d_in[5];
  const float* lt_b2      = (const float*)d_in[6];
  const float* attn_in_w  = (const float*)d_in[7];
  const float* attn_in_b  = (const float*)d_in[8];
  const float* attn_out_w = (const float*)d_in[9];
  const float* attn_out_b = (const float*)d_in[10];
  const float* fus_w      = (const float*)d_in[11];
  const float* fus_b      = (const float*)d_in[12];
  const float* fus_ln_g   = (const float*)d_in[13];
  const float* fus_ln_b   = (const float*)d_in[14];
  float* out = (float*)d_out;
  float* ws  = (float*)d_ws;

  float* Hh = ws;                  // 64 x 1024
  float* KV = Hh + 65536;          // 64 x 1024
  float* QH = KV + 65536;          // 28 x 1024 (32 alloc)
  float* KH = QH + 32768;          // 64 x 1024
  float* VH = KH + 65536;          // 64 x 1024
  float* OA = VH + 65536;          // 28 x 1024
  float* O  = OA + 32768;          // 28 x 1024
  float* UP = O  + 32768;          // 28 x 1024

  k_lat1 <<<1176, 256, 0, stream>>>(x, lt_w1, lt_b1, Hh, out);
  k_lat2 <<<1176, 256, 0, stream>>>(x, Hh, lt_ln_g, lt_ln_b, lt_w2, lt_b2, KV, out);
  k_qkv  <<<1980, 256, 0, stream>>>(x, KV, attn_in_w, attn_in_b, QH, KH, VH, out);
  k_attn <<<728,  256, 0, stream>>>(x, QH, KH, VH, OA, out);
  k_oproj<<<956,  256, 0, stream>>>(x, OA, attn_out_w, attn_out_b, O, out);
  k_fus  <<<956,  256, 0, stream>>>(x, O, fus_w, fus_b, UP, out);
  k_final<<<124,  256, 0, stream>>>(x, UP, fus_ln_g, fus_ln_b, out);
}